// Round 10
// baseline (79.488 us; speedup 1.0000x reference)
//
#include <hip/hip_runtime.h>

typedef __bf16 bf16x8 __attribute__((ext_vector_type(8)));
typedef float f32x4 __attribute__((ext_vector_type(4)));
typedef unsigned short u16x4 __attribute__((ext_vector_type(4)));
typedef unsigned int u32x4 __attribute__((ext_vector_type(4)));

#define LDA 72    // bf16 row pitch (144 B): 16B-aligned rows

__device__ __forceinline__ unsigned short f2bf(float f) {
  __bf16 b = (__bf16)f;                      // hardware RTNE v_cvt
  return __builtin_bit_cast(unsigned short, b);
}

__device__ __forceinline__ u16x4 pack4(f32x4 v) {
  u16x4 r;
  r[0] = f2bf(v[0]); r[1] = f2bf(v[1]); r[2] = f2bf(v[2]); r[3] = f2bf(v[3]);
  return r;
}

__device__ __forceinline__ bf16x8 frag8(const unsigned short* p) {
  typedef unsigned short u16x8v __attribute__((ext_vector_type(8)));
  return __builtin_bit_cast(bf16x8, *reinterpret_cast<const u16x8v*>(p));
}

#define MFMA(a, b, c) __builtin_amdgcn_mfma_f32_16x16x32_bf16(a, b, c, 0, 0, 0)

// ---------------------------------------------------------------------------
// In-register C-frag -> B-frag conversion via permlane butterfly.
// Input: v[si] = C-frag f32x4, value at contraction-row si*16+4g+r, col m0.
// Output: out[kk] = bf16x8 B-frag, element i at k = kk*32 + 8g + i.
// Data moves only among lanes {l15, l15+16, l15+32, l15+48}:
//   step A: permlane32_swap pairs (O[2s1], O[2s1+1])  [lane-bit5 exchange]
//   step B: permlane16_swap pairs (H[e1][0], H[e1][1]) [lane-bit4 exchange]
// Verified element-wise: lane0 k=0 <- own ya[0][0]; lane16 k=8 <- lane32 ya[0][0].
// ---------------------------------------------------------------------------
__device__ __forceinline__ void cfrag2bfrag(const f32x4 v[4], bf16x8 out[2]) {
  unsigned O[4][2];
  #pragma unroll
  for (int si = 0; si < 4; ++si) {
    u16x4 p = pack4(v[si]);
    O[si][0] = (unsigned)p[0] | ((unsigned)p[1] << 16);
    O[si][1] = (unsigned)p[2] | ((unsigned)p[3] << 16);
  }
  unsigned H[2][2][2];  // [s1][g_src1][d]
  #pragma unroll
  for (int s1 = 0; s1 < 2; ++s1)
    #pragma unroll
    for (int d = 0; d < 2; ++d) {
      auto r = __builtin_amdgcn_permlane32_swap(O[2 * s1][d], O[2 * s1 + 1][d], false, false);
      H[s1][0][d] = r[0];
      H[s1][1][d] = r[1];
    }
  #pragma unroll
  for (int e1 = 0; e1 < 2; ++e1) {
    auto r0 = __builtin_amdgcn_permlane16_swap(H[e1][0][0], H[e1][1][0], false, false);
    auto r1 = __builtin_amdgcn_permlane16_swap(H[e1][0][1], H[e1][1][1], false, false);
    u32x4 f;
    f[0] = r0[0]; f[1] = r1[0]; f[2] = r0[1]; f[3] = r1[1];
    out[e1] = __builtin_bit_cast(bf16x8, f);
  }
}

// ---------------------------------------------------------------------------
// Fuse + pack (unchanged from R9): blk = t*8+h:
//   t=0: M_h = Wq_h Wk_h^T * (0.125*log2e);  t=1: N_h = Wv_h Wp_slice_h.
// Output bf16 fragments: block (t,h,kk*4+si), lane l, elem i = W[k][n],
// k = kk*32+8*(l>>4)+i, n = si*16+(l&15).
// ---------------------------------------------------------------------------
__global__ __launch_bounds__(256) void fuse_pack(
    const float* __restrict__ Wq, const float* __restrict__ Wk,
    const float* __restrict__ Wv, const float* __restrict__ Wp,
    unsigned short* __restrict__ wf) {
  __shared__ float A[64 * 65];
  __shared__ float B[64 * 65];
  const int blk = blockIdx.x;           // 0..15
  const int t = blk >> 3, h = blk & 7;
  const int tid = threadIdx.x;
  const float* Asrc = (t ? Wv : Wq) + h * 4096;
  const float* Bsrc = (t ? Wp : Wk) + h * 4096;
  for (int i = tid; i < 4096; i += 256) {
    A[(i >> 6) * 65 + (i & 63)] = Asrc[i];
    B[(i >> 6) * 65 + (i & 63)] = Bsrc[i];
  }
  __syncthreads();
  unsigned short* dst = wf + blk * 4096;
  for (int o = 0; o < 16; ++o) {
    int idx = o * 256 + tid;
    int k = idx >> 6, n = idx & 63;
    float s = 0.f;
    if (t == 0) {
      for (int d = 0; d < 64; ++d) s += A[k * 65 + d] * B[n * 65 + d];
      s *= 0.18033688f;                 // 0.125 * log2(e)
    } else {
      for (int d = 0; d < 64; ++d) s += A[k * 65 + d] * B[d * 65 + n];
    }
    int kk = k >> 5, i = k & 7, lg = (k >> 3) & 3, si = n >> 4, l15 = n & 15;
    dst[((kk * 4 + si) * 64 + lg * 16 + l15) * 8 + i] = f2bf(s);
  }
}

// ---------------------------------------------------------------------------
// Main kernel: 256 threads = 4 waves, 2 batches per block (ILP pair).
// X staged once into Zt[b][0], hoisted fully to registers, region reused as
// the Z double-buffer. Per head (ONE barrier):
//   G = M^T X^T       -> registers -> permlane butterfly -> yB B-frags
//   Z = X N           -> Zt[b][h&1] (only remaining LDS roundtrip)
//   S^T = X G         -> in-reg softmax -> normalize -> butterfly -> pb
//   barrier; out^T += Zt^T P^T (register acc across heads)
// ---------------------------------------------------------------------------
__global__ __launch_bounds__(256, 2) void mha_fwd(
    const float* __restrict__ x, const unsigned short* __restrict__ wf,
    const float* __restrict__ bproj, float* __restrict__ out) {
  __shared__ __attribute__((aligned(16))) unsigned short Zt[2][2][64 * LDA];  // [batch][dbuf]

  const int tid  = threadIdx.x;
  const int lane = tid & 63;
  const int w    = tid >> 6;
  const int l15  = lane & 15;
  const int g    = lane >> 4;
  const int m0   = w * 16 + l15;
  const int kcol = 8 * g;
  const int rowA = m0 * LDA;

  // ---- stage both batches (fp32 -> bf16, row-major [s][c]) into Zt[bt][0] ----
  const float* xb = x + (size_t)blockIdx.x * 8192;
  #pragma unroll
  for (int it = 0; it < 8; ++it) {
    int idx = it * 1024 + tid * 4;
    float4 v = *reinterpret_cast<const float4*>(xb + idx);
    f32x4 vv = {v.x, v.y, v.z, v.w};
    int bt = idx >> 12, rem = idx & 4095;
    *reinterpret_cast<u16x4*>(&Zt[bt][0][(rem >> 6) * LDA + (rem & 63)]) = pack4(vv);
  }
  __syncthreads();

  // ---- hoist ALL X fragments into registers ----
  bf16x8 xbt[2][2];      // X^T B-frags (own row m0)
  bf16x8 xa[2][2][4];    // X A-frags (rows si*16+l15)
  #pragma unroll
  for (int b = 0; b < 2; ++b) {
    xbt[b][0] = frag8(&Zt[b][0][rowA + kcol]);
    xbt[b][1] = frag8(&Zt[b][0][rowA + 32 + kcol]);
    #pragma unroll
    for (int kk = 0; kk < 2; ++kk)
      #pragma unroll
      for (int si = 0; si < 4; ++si)
        xa[b][kk][si] = frag8(&Zt[b][0][(si * 16 + l15) * LDA + kk * 32 + kcol]);
  }
  __syncthreads();  // all waves done reading X; Zt reusable as Z double-buffer

  // ---- out^T accumulators, bias-init: row n = nj*16+4g+r, col m0 ----
  f32x4 oacc[2][4];
  #pragma unroll
  for (int nj = 0; nj < 4; ++nj) {
    float4 bv = *reinterpret_cast<const float4*>(&bproj[nj * 16 + 4 * g]);
    oacc[0][nj] = f32x4{bv.x, bv.y, bv.z, bv.w};
    oacc[1][nj] = oacc[0][nj];
  }

  for (int h = 0; h < 8; ++h) {
    const unsigned short* mf = wf + h * 4096;          // M^T A-frags
    const unsigned short* nf = wf + 32768 + h * 4096;  // N B-frags
    unsigned short* zbuf = &Zt[0][h & 1][0];
    const int zsel = (h & 1) ? 1 : 0;  // (for clarity; indexing via Zt[b][h&1])

    bf16x8 Mf[2][4], Nf[2];
    #pragma unroll
    for (int kk = 0; kk < 2; ++kk) {
      Nf[kk] = frag8(&nf[(kk * 4 + w) * 512 + lane * 8]);
      #pragma unroll
      for (int si = 0; si < 4; ++si)
        Mf[kk][si] = frag8(&mf[(kk * 4 + si) * 512 + lane * 8]);
    }
    (void)zbuf; (void)zsel;

    bf16x8 pb[2][2];
    #pragma unroll
    for (int b = 0; b < 2; ++b) {
      unsigned short* ztb = &Zt[b][h & 1][0];

      // ---- G = M^T X^T : C-frag ya, rows c = si*16+4g+r, col m0 ----
      f32x4 ya[4] = {};
      #pragma unroll
      for (int kk = 0; kk < 2; ++kk)
        #pragma unroll
        for (int si = 0; si < 4; ++si)
          ya[si] = MFMA(Mf[kk][si], xbt[b][kk], ya[si]);
      bf16x8 yB[2];
      cfrag2bfrag(ya, yB);               // in-register: no LDS roundtrip

      // ---- Z = X N : rows s, col m0 -> Zt[b][h&1][m0][s] (shared) ----
      f32x4 za[4] = {};
      #pragma unroll
      for (int kk = 0; kk < 2; ++kk)
        #pragma unroll
        for (int si = 0; si < 4; ++si)
          za[si] = MFMA(xa[b][kk][si], Nf[kk], za[si]);
      #pragma unroll
      for (int si = 0; si < 4; ++si)
        *reinterpret_cast<u16x4*>(&ztb[rowA + si * 16 + 4 * g]) = pack4(za[si]);

      // ---- S^T = X G : rows s, col m0 ----
      f32x4 sa[4] = {};
      #pragma unroll
      for (int kk = 0; kk < 2; ++kk)
        #pragma unroll
        for (int si = 0; si < 4; ++si)
          sa[si] = MFMA(xa[b][kk][si], yB[kk], sa[si]);

      // ---- in-register softmax (scale+log2e baked into M; no max-sub) ----
      float sum = 0.f;
      #pragma unroll
      for (int si = 0; si < 4; ++si)
        #pragma unroll
        for (int r = 0; r < 4; ++r) {
          int s = si * 16 + 4 * g + r;
          float e = (s <= m0) ? exp2f(sa[si][r]) : 0.f;
          sa[si][r] = e;
          sum += e;
        }
      sum += __shfl_xor(sum, 16);
      sum += __shfl_xor(sum, 32);
      float rinv = __builtin_amdgcn_rcpf(sum);
      #pragma unroll
      for (int si = 0; si < 4; ++si) sa[si] *= rinv;

      cfrag2bfrag(sa, pb[b]);            // P^T B-frags, in-register
    }
    __syncthreads();  // [1/head] Zt[.][h&1] visible; dbuf removes WAR hazard

    // ---- out^T += Z^T P^T : rows n = nj*16+4g+r, col m0 ----
    #pragma unroll
    for (int b = 0; b < 2; ++b) {
      unsigned short* ztb = &Zt[b][h & 1][0];
      #pragma unroll
      for (int kk = 0; kk < 2; ++kk)
        #pragma unroll
        for (int nj = 0; nj < 4; ++nj)
          oacc[b][nj] = MFMA(frag8(&ztb[(nj * 16 + l15) * LDA + kk * 32 + kcol]),
                             pb[b][kk], oacc[b][nj]);
    }
  }

  // ---- store fp32 outputs: out[b][m0][n], n = nj*16+4g+r ----
  #pragma unroll
  for (int b = 0; b < 2; ++b) {
    float* op = out + (size_t)blockIdx.x * 8192 + b * 4096 + m0 * 64;
    #pragma unroll
    for (int nj = 0; nj < 4; ++nj) {
      float4 st = {oacc[b][nj][0], oacc[b][nj][1], oacc[b][nj][2], oacc[b][nj][3]};
      *reinterpret_cast<float4*>(&op[nj * 16 + 4 * g]) = st;
    }
  }
}

extern "C" void kernel_launch(void* const* d_in, const int* in_sizes, int n_in,
                              void* d_out, int out_size, void* d_ws, size_t ws_size,
                              hipStream_t stream) {
  const float* x  = (const float*)d_in[0];
  const float* Wq = (const float*)d_in[1];
  const float* Wk = (const float*)d_in[2];
  const float* Wv = (const float*)d_in[3];
  const float* Wp = (const float*)d_in[4];
  const float* bp = (const float*)d_in[5];
  unsigned short* wf = (unsigned short*)d_ws;  // 65536 bf16 = 128 KB fused-weight frags

  fuse_pack<<<dim3(16), dim3(256), 0, stream>>>(Wq, Wk, Wv, Wp, wf);
  mha_fwd<<<dim3(1024), dim3(256), 0, stream>>>(x, wf, bp, (float*)d_out);
}

// Round 11
// 61.434 us; speedup vs baseline: 1.2939x; 1.2939x over previous
//
#include <hip/hip_runtime.h>

typedef __bf16 bf16x8 __attribute__((ext_vector_type(8)));
typedef float f32x4 __attribute__((ext_vector_type(4)));
typedef unsigned short u16x4 __attribute__((ext_vector_type(4)));
typedef unsigned int u32x4 __attribute__((ext_vector_type(4)));

#define LDA 72    // bf16 row pitch (144 B): 16B-aligned rows

__device__ __forceinline__ unsigned short f2bf(float f) {
  __bf16 b = (__bf16)f;                      // hardware RTNE v_cvt
  return __builtin_bit_cast(unsigned short, b);
}

__device__ __forceinline__ u16x4 pack4(f32x4 v) {
  u16x4 r;
  r[0] = f2bf(v[0]); r[1] = f2bf(v[1]); r[2] = f2bf(v[2]); r[3] = f2bf(v[3]);
  return r;
}

__device__ __forceinline__ bf16x8 frag8(const unsigned short* p) {
  typedef unsigned short u16x8v __attribute__((ext_vector_type(8)));
  return __builtin_bit_cast(bf16x8, *reinterpret_cast<const u16x8v*>(p));
}

#define MFMA(a, b, c) __builtin_amdgcn_mfma_f32_16x16x32_bf16(a, b, c, 0, 0, 0)

// ---------------------------------------------------------------------------
// In-register C-frag -> A/B-frag conversion (R10-validated permlane butterfly).
// Input: v[t] = C-frag f32x4 for contraction-tile t (value at k-row t*16+4g+r,
// out-col at l15). Output: out[kk] elem i at k = kk*32 + 8g + i, same col l15.
// A-frag and B-frag share this lane layout, so the result serves both roles.
// ---------------------------------------------------------------------------
__device__ __forceinline__ void cfrag2bfrag(const f32x4 v[4], bf16x8 out[2]) {
  unsigned O[4][2];
  #pragma unroll
  for (int si = 0; si < 4; ++si) {
    u16x4 p = pack4(v[si]);
    O[si][0] = (unsigned)p[0] | ((unsigned)p[1] << 16);
    O[si][1] = (unsigned)p[2] | ((unsigned)p[3] << 16);
  }
  unsigned H[2][2][2];
  #pragma unroll
  for (int s1 = 0; s1 < 2; ++s1)
    #pragma unroll
    for (int d = 0; d < 2; ++d) {
      auto r = __builtin_amdgcn_permlane32_swap(O[2 * s1][d], O[2 * s1 + 1][d], false, false);
      H[s1][0][d] = r[0];
      H[s1][1][d] = r[1];
    }
  #pragma unroll
  for (int e1 = 0; e1 < 2; ++e1) {
    auto r0 = __builtin_amdgcn_permlane16_swap(H[e1][0][0], H[e1][1][0], false, false);
    auto r1 = __builtin_amdgcn_permlane16_swap(H[e1][0][1], H[e1][1][1], false, false);
    u32x4 f;
    f[0] = r0[0]; f[1] = r1[0]; f[2] = r0[1]; f[3] = r1[1];
    out[e1] = __builtin_bit_cast(bf16x8, f);
  }
}

// ---------------------------------------------------------------------------
// Fuse + pack (unchanged): blk = t*8+h:
//   t=0: M_h = Wq_h Wk_h^T * (0.125*log2e);  t=1: N_h = Wv_h Wp_slice_h.
// bf16 fragments: block (t,h,kk*4+si), lane l, elem i = W[k][n],
// k = kk*32+8*(l>>4)+i, n = si*16+(l&15).
// ---------------------------------------------------------------------------
__global__ __launch_bounds__(256) void fuse_pack(
    const float* __restrict__ Wq, const float* __restrict__ Wk,
    const float* __restrict__ Wv, const float* __restrict__ Wp,
    unsigned short* __restrict__ wf) {
  __shared__ float A[64 * 65];
  __shared__ float B[64 * 65];
  const int blk = blockIdx.x;           // 0..15
  const int t = blk >> 3, h = blk & 7;
  const int tid = threadIdx.x;
  const float* Asrc = (t ? Wv : Wq) + h * 4096;
  const float* Bsrc = (t ? Wp : Wk) + h * 4096;
  for (int i = tid; i < 4096; i += 256) {
    A[(i >> 6) * 65 + (i & 63)] = Asrc[i];
    B[(i >> 6) * 65 + (i & 63)] = Bsrc[i];
  }
  __syncthreads();
  unsigned short* dst = wf + blk * 4096;
  for (int o = 0; o < 16; ++o) {
    int idx = o * 256 + tid;
    int k = idx >> 6, n = idx & 63;
    float s = 0.f;
    if (t == 0) {
      for (int d = 0; d < 64; ++d) s += A[k * 65 + d] * B[n * 65 + d];
      s *= 0.18033688f;                 // 0.125 * log2(e)
    } else {
      for (int d = 0; d < 64; ++d) s += A[k * 65 + d] * B[d * 65 + n];
    }
    int kk = k >> 5, i = k & 7, lg = (k >> 3) & 3, si = n >> 4, l15 = n & 15;
    dst[((kk * 4 + si) * 64 + lg * 16 + l15) * 8 + i] = f2bf(s);
  }
}

// ---------------------------------------------------------------------------
// Main kernel: 256 threads = 4 waves; ONE WAVE = ONE BATCH, zero barriers in
// the head loop, zero LDS after the staging prologue. Per head (per wave):
//   G = M^T X^T  : 32 MFMA, per-mt col -> butterfly -> gB
//   S = X G      : 32 MFMA, per-mt col -> in-reg softmax -> butterfly -> pA
//   Z = X N      : 32 MFMA, per-nt col -> butterfly -> zB
//   out += P Z   : 32 MFMA into persistent oacc (bias-init)
// X lives entirely in registers (A/B dual-role frags). All 2048 batches are
// resident on the chip at once (2 waves/SIMD) -> latency hidden by TLP+ILP.
// ---------------------------------------------------------------------------
__global__ __launch_bounds__(256, 2) void mha_fwd(
    const float* __restrict__ x, const unsigned short* __restrict__ wf,
    const float* __restrict__ bproj, float* __restrict__ out) {
  __shared__ __attribute__((aligned(16))) unsigned short Xs[4][64 * LDA];

  const int tid  = threadIdx.x;
  const int lane = tid & 63;
  const int w    = tid >> 6;
  const int l15  = lane & 15;
  const int g    = lane >> 4;
  const int kcol = 8 * g;

  // ---- stage 4 batches (fp32 -> bf16, row-major [s][c]), coalesced ----
  const float* xb = x + (size_t)blockIdx.x * 16384;
  #pragma unroll
  for (int it = 0; it < 16; ++it) {
    int idx = it * 1024 + tid * 4;
    float4 v = *reinterpret_cast<const float4*>(xb + idx);
    f32x4 vv = {v.x, v.y, v.z, v.w};
    int bt = idx >> 12, rem = idx & 4095;
    *reinterpret_cast<u16x4*>(&Xs[bt][(rem >> 6) * LDA + (rem & 63)]) = pack4(vv);
  }
  __syncthreads();  // the ONLY barrier

  // ---- hoist this wave's X into registers (dual-role A/B frags) ----
  // xf[cc][t]: element X[t*16+l15][cc*32 + 8g + i]
  bf16x8 xf[2][4];
  #pragma unroll
  for (int cc = 0; cc < 2; ++cc)
    #pragma unroll
    for (int t = 0; t < 4; ++t)
      xf[cc][t] = frag8(&Xs[w][(t * 16 + l15) * LDA + cc * 32 + kcol]);

  // ---- persistent out C-frags [mt][nt], bias-init (row m=mt*16+4g+r, col n=nt*16+l15) ----
  f32x4 oacc[4][4];
  #pragma unroll
  for (int nt = 0; nt < 4; ++nt) {
    float bias = bproj[nt * 16 + l15];
    f32x4 bv = {bias, bias, bias, bias};
    #pragma unroll
    for (int mt = 0; mt < 4; ++mt) oacc[mt][nt] = bv;
  }

  for (int h = 0; h < 8; ++h) {
    const unsigned short* mf = wf + h * 4096;          // M^T A-frags [kk*4+ct]
    const unsigned short* nf = wf + 32768 + h * 4096;  // N  B-frags [kk*4+nt]

    // ---- G = M^T X^T, per output col-tile mt; immediate butterfly ----
    bf16x8 gB[2][4];
    #pragma unroll
    for (int mt = 0; mt < 4; ++mt) {
      f32x4 gc[4] = {};
      #pragma unroll
      for (int kk = 0; kk < 2; ++kk)
        #pragma unroll
        for (int ct = 0; ct < 4; ++ct)
          gc[ct] = MFMA(frag8(&mf[(kk * 4 + ct) * 512 + lane * 8]), xf[kk][mt], gc[ct]);
      bf16x8 o2[2];
      cfrag2bfrag(gc, o2);
      gB[0][mt] = o2[0]; gB[1][mt] = o2[1];
    }

    // ---- S = X G, per col mt; softmax in-register; butterfly -> pA ----
    bf16x8 pA[2][4];
    #pragma unroll
    for (int mt = 0; mt < 4; ++mt) {
      f32x4 sc[4] = {};
      #pragma unroll
      for (int cc = 0; cc < 2; ++cc)
        #pragma unroll
        for (int st = 0; st < 4; ++st)
          sc[st] = MFMA(xf[cc][st], gB[cc][mt], sc[st]);
      const int m = mt * 16 + l15;
      float sum = 0.f;
      #pragma unroll
      for (int st = 0; st < 4; ++st)
        #pragma unroll
        for (int r = 0; r < 4; ++r) {
          int s = st * 16 + 4 * g + r;
          float e = (s <= m) ? exp2f(sc[st][r]) : 0.f;   // scale+log2e in M
          sc[st][r] = e;
          sum += e;
        }
      sum += __shfl_xor(sum, 16);
      sum += __shfl_xor(sum, 32);
      float rinv = __builtin_amdgcn_rcpf(sum);
      #pragma unroll
      for (int st = 0; st < 4; ++st) sc[st] *= rinv;
      bf16x8 o2[2];
      cfrag2bfrag(sc, o2);
      pA[0][mt] = o2[0]; pA[1][mt] = o2[1];
    }

    // ---- Z = X N, per col nt; butterfly -> zB ----
    bf16x8 zB[2][4];
    #pragma unroll
    for (int nt = 0; nt < 4; ++nt) {
      bf16x8 nf0 = frag8(&nf[(0 * 4 + nt) * 512 + lane * 8]);
      bf16x8 nf1 = frag8(&nf[(1 * 4 + nt) * 512 + lane * 8]);
      f32x4 zc[4] = {};
      #pragma unroll
      for (int st = 0; st < 4; ++st) {
        zc[st] = MFMA(xf[0][st], nf0, zc[st]);
        zc[st] = MFMA(xf[1][st], nf1, zc[st]);
      }
      bf16x8 o2[2];
      cfrag2bfrag(zc, o2);
      zB[0][nt] = o2[0]; zB[1][nt] = o2[1];
    }

    // ---- out += P Z ----
    #pragma unroll
    for (int mt = 0; mt < 4; ++mt)
      #pragma unroll
      for (int nt = 0; nt < 4; ++nt) {
        oacc[mt][nt] = MFMA(pA[0][mt], zB[0][nt], oacc[mt][nt]);
        oacc[mt][nt] = MFMA(pA[1][mt], zB[1][nt], oacc[mt][nt]);
      }
  }

  // ---- store fp32 output: out[b][mt*16+4g+r][nt*16+l15] ----
  float* ob = out + ((size_t)blockIdx.x * 4 + w) * 4096;
  #pragma unroll
  for (int mt = 0; mt < 4; ++mt)
    #pragma unroll
    for (int r = 0; r < 4; ++r) {
      float* orow = ob + (mt * 16 + 4 * g + r) * 64;
      #pragma unroll
      for (int nt = 0; nt < 4; ++nt)
        orow[nt * 16 + l15] = oacc[mt][nt][r];
    }
}

extern "C" void kernel_launch(void* const* d_in, const int* in_sizes, int n_in,
                              void* d_out, int out_size, void* d_ws, size_t ws_size,
                              hipStream_t stream) {
  const float* x  = (const float*)d_in[0];
  const float* Wq = (const float*)d_in[1];
  const float* Wk = (const float*)d_in[2];
  const float* Wv = (const float*)d_in[3];
  const float* Wp = (const float*)d_in[4];
  const float* bp = (const float*)d_in[5];
  unsigned short* wf = (unsigned short*)d_ws;  // 65536 bf16 = 128 KB fused-weight frags

  fuse_pack<<<dim3(16), dim3(256), 0, stream>>>(Wq, Wk, Wv, Wp, wf);
  mha_fwd<<<dim3(512), dim3(256), 0, stream>>>(x, wf, bp, (float*)d_out);
}

// Round 12
// 57.896 us; speedup vs baseline: 1.3729x; 1.0611x over previous
//
#include <hip/hip_runtime.h>

typedef __bf16 bf16x8 __attribute__((ext_vector_type(8)));
typedef float f32x4 __attribute__((ext_vector_type(4)));
typedef unsigned short u16x4 __attribute__((ext_vector_type(4)));
typedef unsigned int u32x4 __attribute__((ext_vector_type(4)));

#define LDA 72    // bf16 row pitch (144 B): 16B-aligned rows

__device__ __forceinline__ unsigned short f2bf(float f) {
  __bf16 b = (__bf16)f;                      // hardware RTNE v_cvt
  return __builtin_bit_cast(unsigned short, b);
}

__device__ __forceinline__ u16x4 pack4(f32x4 v) {
  u16x4 r;
  r[0] = f2bf(v[0]); r[1] = f2bf(v[1]); r[2] = f2bf(v[2]); r[3] = f2bf(v[3]);
  return r;
}

__device__ __forceinline__ bf16x8 frag8(const unsigned short* p) {
  typedef unsigned short u16x8v __attribute__((ext_vector_type(8)));
  return __builtin_bit_cast(bf16x8, *reinterpret_cast<const u16x8v*>(p));
}

#define MFMA(a, b, c) __builtin_amdgcn_mfma_f32_16x16x32_bf16(a, b, c, 0, 0, 0)

// ---------------------------------------------------------------------------
// In-register C-frag -> A/B-frag conversion (validated permlane butterfly).
// v[t] = C-frag f32x4 (k-row t*16+4g+r, col l15) -> out[kk] elem i at
// k = kk*32 + 8g + i, same col. Serves as A-frag or B-frag (same layout).
// ---------------------------------------------------------------------------
__device__ __forceinline__ void cfrag2bfrag(const f32x4 v[4], bf16x8 out[2]) {
  unsigned O[4][2];
  #pragma unroll
  for (int si = 0; si < 4; ++si) {
    u16x4 p = pack4(v[si]);
    O[si][0] = (unsigned)p[0] | ((unsigned)p[1] << 16);
    O[si][1] = (unsigned)p[2] | ((unsigned)p[3] << 16);
  }
  unsigned H[2][2][2];
  #pragma unroll
  for (int s1 = 0; s1 < 2; ++s1)
    #pragma unroll
    for (int d = 0; d < 2; ++d) {
      auto r = __builtin_amdgcn_permlane32_swap(O[2 * s1][d], O[2 * s1 + 1][d], false, false);
      H[s1][0][d] = r[0];
      H[s1][1][d] = r[1];
    }
  #pragma unroll
  for (int e1 = 0; e1 < 2; ++e1) {
    auto r0 = __builtin_amdgcn_permlane16_swap(H[e1][0][0], H[e1][1][0], false, false);
    auto r1 = __builtin_amdgcn_permlane16_swap(H[e1][0][1], H[e1][1][1], false, false);
    u32x4 f;
    f[0] = r0[0]; f[1] = r1[0]; f[2] = r0[1]; f[3] = r1[1];
    out[e1] = __builtin_bit_cast(bf16x8, f);
  }
}

// ---------------------------------------------------------------------------
// Fuse + pack (unchanged): blk = t*8+h:
//   t=0: M_h = Wq_h Wk_h^T * (0.125*log2e);  t=1: N_h = Wv_h Wp_slice_h.
// bf16 fragments: block (t,h,kk*4+si), lane l, elem i = W[k][n],
// k = kk*32+8*(l>>4)+i, n = si*16+(l&15).
// ---------------------------------------------------------------------------
__global__ __launch_bounds__(256) void fuse_pack(
    const float* __restrict__ Wq, const float* __restrict__ Wk,
    const float* __restrict__ Wv, const float* __restrict__ Wp,
    unsigned short* __restrict__ wf) {
  __shared__ float A[64 * 65];
  __shared__ float B[64 * 65];
  const int blk = blockIdx.x;           // 0..15
  const int t = blk >> 3, h = blk & 7;
  const int tid = threadIdx.x;
  const float* Asrc = (t ? Wv : Wq) + h * 4096;
  const float* Bsrc = (t ? Wp : Wk) + h * 4096;
  for (int i = tid; i < 4096; i += 256) {
    A[(i >> 6) * 65 + (i & 63)] = Asrc[i];
    B[(i >> 6) * 65 + (i & 63)] = Bsrc[i];
  }
  __syncthreads();
  unsigned short* dst = wf + blk * 4096;
  for (int o = 0; o < 16; ++o) {
    int idx = o * 256 + tid;
    int k = idx >> 6, n = idx & 63;
    float s = 0.f;
    if (t == 0) {
      for (int d = 0; d < 64; ++d) s += A[k * 65 + d] * B[n * 65 + d];
      s *= 0.18033688f;                 // 0.125 * log2(e)
    } else {
      for (int d = 0; d < 64; ++d) s += A[k * 65 + d] * B[d * 65 + n];
    }
    int kk = k >> 5, i = k & 7, lg = (k >> 3) & 3, si = n >> 4, l15 = n & 15;
    dst[((kk * 4 + si) * 64 + lg * 16 + l15) * 8 + i] = f2bf(s);
  }
}

// ---------------------------------------------------------------------------
// Main kernel: 256 threads = 4 waves; ONE WAVE = ONE BATCH, zero barriers in
// the head loop, zero LDS after staging. Per head (per wave):
//   G = M^T X^T  : 32 MFMA (Mf hoisted once/head)
//   S = X G      : causal tile-skip -> 20 MFMA; masked exp only on diagonal
//   Z = X N      : 32 MFMA
//   out += P Z   : k-range skip (pA zero beyond s<=m) -> 24 MFMA
// 108 MFMA/head/wave. All data in registers between MFMAs (butterflies).
// ---------------------------------------------------------------------------
__global__ __launch_bounds__(256, 2) void mha_fwd(
    const float* __restrict__ x, const unsigned short* __restrict__ wf,
    const float* __restrict__ bproj, float* __restrict__ out) {
  __shared__ __attribute__((aligned(16))) unsigned short Xs[4][64 * LDA];

  const int tid  = threadIdx.x;
  const int lane = tid & 63;
  const int w    = tid >> 6;
  const int l15  = lane & 15;
  const int g    = lane >> 4;
  const int kcol = 8 * g;

  // ---- stage 4 batches (fp32 -> bf16, row-major [s][c]), coalesced ----
  const float* xb = x + (size_t)blockIdx.x * 16384;
  #pragma unroll
  for (int it = 0; it < 16; ++it) {
    int idx = it * 1024 + tid * 4;
    float4 v = *reinterpret_cast<const float4*>(xb + idx);
    f32x4 vv = {v.x, v.y, v.z, v.w};
    int bt = idx >> 12, rem = idx & 4095;
    *reinterpret_cast<u16x4*>(&Xs[bt][(rem >> 6) * LDA + (rem & 63)]) = pack4(vv);
  }
  __syncthreads();  // the ONLY barrier

  // ---- hoist this wave's X into registers (dual-role A/B frags) ----
  bf16x8 xf[2][4];   // element X[t*16+l15][cc*32 + 8g + i]
  #pragma unroll
  for (int cc = 0; cc < 2; ++cc)
    #pragma unroll
    for (int t = 0; t < 4; ++t)
      xf[cc][t] = frag8(&Xs[w][(t * 16 + l15) * LDA + cc * 32 + kcol]);

  // ---- persistent out C-frags [mt][nt], bias-init ----
  f32x4 oacc[4][4];
  #pragma unroll
  for (int nt = 0; nt < 4; ++nt) {
    float bias = bproj[nt * 16 + l15];
    f32x4 bv = {bias, bias, bias, bias};
    #pragma unroll
    for (int mt = 0; mt < 4; ++mt) oacc[mt][nt] = bv;
  }

  for (int h = 0; h < 8; ++h) {
    const unsigned short* mf = wf + h * 4096;          // M^T A-frags [kk*4+ct]
    const unsigned short* nf = wf + 32768 + h * 4096;  // N  B-frags [kk*4+nt]

    // ---- hoist this head's weight fragments (8 + 8 dwordx4 loads) ----
    bf16x8 Mf[2][4], Nf[2][4];
    #pragma unroll
    for (int kk = 0; kk < 2; ++kk)
      #pragma unroll
      for (int ct = 0; ct < 4; ++ct) {
        Mf[kk][ct] = frag8(&mf[(kk * 4 + ct) * 512 + lane * 8]);
        Nf[kk][ct] = frag8(&nf[(kk * 4 + ct) * 512 + lane * 8]);
      }

    // ---- G = M^T X^T, per output col-tile mt; immediate butterfly ----
    bf16x8 gB[2][4];
    #pragma unroll
    for (int mt = 0; mt < 4; ++mt) {
      f32x4 gc[4] = {};
      #pragma unroll
      for (int kk = 0; kk < 2; ++kk)
        #pragma unroll
        for (int ct = 0; ct < 4; ++ct)
          gc[ct] = MFMA(Mf[kk][ct], xf[kk][mt], gc[ct]);
      bf16x8 o2[2];
      cfrag2bfrag(gc, o2);
      gB[0][mt] = o2[0]; gB[1][mt] = o2[1];
    }

    // ---- S = X G with causal tile-skip; softmax; butterfly -> pA ----
    bf16x8 pA[2][4];
    #pragma unroll
    for (int mt = 0; mt < 4; ++mt) {
      f32x4 sc[4] = {};   // st > mt stays zero (fully masked tiles skipped)
      #pragma unroll
      for (int cc = 0; cc < 2; ++cc)
        #pragma unroll
        for (int st = 0; st < 4; ++st)
          if (st <= mt)
            sc[st] = MFMA(xf[cc][st], gB[cc][mt], sc[st]);
      const int m = mt * 16 + l15;
      float sum = 0.f;
      #pragma unroll
      for (int st = 0; st < 4; ++st) {
        if (st < mt) {                    // fully unmasked tile
          #pragma unroll
          for (int r = 0; r < 4; ++r) { float e = exp2f(sc[st][r]); sc[st][r] = e; sum += e; }
        } else if (st == mt) {            // diagonal tile: mask
          #pragma unroll
          for (int r = 0; r < 4; ++r) {
            int s = st * 16 + 4 * g + r;
            float e = (s <= m) ? exp2f(sc[st][r]) : 0.f;
            sc[st][r] = e; sum += e;
          }
        }
      }
      sum += __shfl_xor(sum, 16);
      sum += __shfl_xor(sum, 32);
      float rinv = __builtin_amdgcn_rcpf(sum);
      #pragma unroll
      for (int st = 0; st < 4; ++st)
        if (st <= mt) sc[st] *= rinv;
      bf16x8 o2[2];
      cfrag2bfrag(sc, o2);
      pA[0][mt] = o2[0]; pA[1][mt] = o2[1];
    }

    // ---- Z = X N, per col nt; butterfly -> zB ----
    bf16x8 zB[2][4];
    #pragma unroll
    for (int nt = 0; nt < 4; ++nt) {
      f32x4 zc[4] = {};
      #pragma unroll
      for (int st = 0; st < 4; ++st) {
        zc[st] = MFMA(xf[0][st], Nf[0][nt], zc[st]);
        zc[st] = MFMA(xf[1][st], Nf[1][nt], zc[st]);
      }
      bf16x8 o2[2];
      cfrag2bfrag(zc, o2);
      zB[0][nt] = o2[0]; zB[1][nt] = o2[1];
    }

    // ---- out += P Z ; skip cc=1 where P's k-range (s<=m) is within cc=0 ----
    #pragma unroll
    for (int mt = 0; mt < 4; ++mt)
      #pragma unroll
      for (int nt = 0; nt < 4; ++nt) {
        oacc[mt][nt] = MFMA(pA[0][mt], zB[0][nt], oacc[mt][nt]);
        if (mt >= 2)
          oacc[mt][nt] = MFMA(pA[1][mt], zB[1][nt], oacc[mt][nt]);
      }
  }

  // ---- store fp32 output: out[b][mt*16+4g+r][nt*16+l15] ----
  float* ob = out + ((size_t)blockIdx.x * 4 + w) * 4096;
  #pragma unroll
  for (int mt = 0; mt < 4; ++mt)
    #pragma unroll
    for (int r = 0; r < 4; ++r) {
      float* orow = ob + (mt * 16 + 4 * g + r) * 64;
      #pragma unroll
      for (int nt = 0; nt < 4; ++nt)
        orow[nt * 16 + l15] = oacc[mt][nt][r];
    }
}

extern "C" void kernel_launch(void* const* d_in, const int* in_sizes, int n_in,
                              void* d_out, int out_size, void* d_ws, size_t ws_size,
                              hipStream_t stream) {
  const float* x  = (const float*)d_in[0];
  const float* Wq = (const float*)d_in[1];
  const float* Wk = (const float*)d_in[2];
  const float* Wv = (const float*)d_in[3];
  const float* Wp = (const float*)d_in[4];
  const float* bp = (const float*)d_in[5];
  unsigned short* wf = (unsigned short*)d_ws;  // 65536 bf16 = 128 KB fused-weight frags

  fuse_pack<<<dim3(16), dim3(256), 0, stream>>>(Wq, Wk, Wv, Wp, wf);
  mha_fwd<<<dim3(512), dim3(256), 0, stream>>>(x, wf, bp, (float*)d_out);
}